// Round 13
// baseline (227.185 us; speedup 1.0000x reference)
//
#include <hip/hip_runtime.h>
#include <hip/hip_bf16.h>

#define NT 4096      // tokens
#define DIM 768
#define NE 1536      // experts
#define ED 64        // expert dim
#define GAP_THR 8e-3f
#define MAXG 1920    // >= max groups: (4096 + 7*1536)/8 = 1856

typedef __attribute__((ext_vector_type(8))) _Float16 half8v;
typedef __attribute__((ext_vector_type(4))) _Float16 half4v;
typedef __attribute__((ext_vector_type(4))) float f32x4;

__device__ __forceinline__ void gload16(const void* g, void* l) {
  __builtin_amdgcn_global_load_lds((const __attribute__((address_space(1))) void*)g,
                                   (__attribute__((address_space(3))) void*)l, 16, 0, 0);
}

__device__ __forceinline__ void top2_merge(float& m1, int& i1, float& m2, int& i2,
                                           float om1, int oi1, float om2, int oi2) {
  if (om1 > m1 || (om1 == m1 && oi1 < i1)) {
    if (m1 > om2 || (m1 == om2 && i1 < oi2)) { m2 = m1; i2 = i1; }
    else { m2 = om2; i2 = oi2; }
    m1 = om1; i1 = oi1;
  } else {
    if (om1 > m2 || (om1 == m2 && oi1 < i2)) { m2 = om1; i2 = oi1; }
  }
}

// ---- Kernel 0: x -> fp16; gate_w -> fp16 hi + fp16 lo (exact to 2^-21) ----
__global__ __launch_bounds__(256) void split_all(
    const float* __restrict__ x, const float* __restrict__ gw,
    _Float16* __restrict__ xh, _Float16* __restrict__ gh, _Float16* __restrict__ gl,
    int* __restrict__ rc_cnt, int* __restrict__ counts) {
  if (blockIdx.x == 0) {
    for (int j = threadIdx.x; j < NE; j += 256) counts[j] = 0;
    if (threadIdx.x == 0) *rc_cnt = 0;
  }
  const int nx4 = NT * DIM / 4;
  const int ng4 = NE * DIM / 4;
  int i = blockIdx.x * 256 + threadIdx.x;
  if (i < nx4) {
    float4 v = ((const float4*)x)[i];
    half4v hv = {(_Float16)v.x, (_Float16)v.y, (_Float16)v.z, (_Float16)v.w};
    ((half4v*)xh)[i] = hv;
  } else {
    int j = i - nx4;
    if (j >= ng4) return;
    float4 v = ((const float4*)gw)[j];
    half4v hv = {(_Float16)v.x, (_Float16)v.y, (_Float16)v.z, (_Float16)v.w};
    half4v lv = {(_Float16)(v.x - (float)hv[0]), (_Float16)(v.y - (float)hv[1]),
                 (_Float16)(v.z - (float)hv[2]), (_Float16)(v.w - (float)hv[3])};
    ((half4v*)gh)[j] = hv;
    ((half4v*)gl)[j] = lv;
  }
}

// ---- Kernel 1: gating GEMM (fp16 2-pass MFMA) + fused partial softmax ----
__global__ __launch_bounds__(256) void gate_mfma(
    const _Float16* __restrict__ xh, const _Float16* __restrict__ gh,
    const _Float16* __restrict__ gl, const float* __restrict__ gb,
    const float* __restrict__ noise, float4* __restrict__ part_a,
    int* __restrict__ part_i2) {
  __shared__ __align__(16) _Float16 sA[2][64 * 32];
  __shared__ __align__(16) _Float16 sBh[2][128 * 32];
  __shared__ __align__(16) _Float16 sBl[2][128 * 32];
  const int tid = threadIdx.x;
  const int w = tid >> 6, lane = tid & 63;
  const int bm = blockIdx.x, bn = blockIdx.y;
  const int fr = lane & 15, fg = lane >> 4;
  const int gsw = fg ^ ((fr >> 1) & 3);

  f32x4 acc[4][2];
#pragma unroll
  for (int i = 0; i < 4; i++)
#pragma unroll
    for (int j = 0; j < 2; j++) acc[i][j] = (f32x4){0.f, 0.f, 0.f, 0.f};

  const size_t arow = (size_t)bm * 64 * DIM;
  const size_t brow = (size_t)bn * 128 * DIM;
  const int rA = tid >> 2;
  const int sg = (tid & 3) ^ ((rA >> 1) & 3);
  const int dA = w * 512;

#define STAGE(b, kt) do {                                                     \
    gload16(xh + arow + (size_t)rA * DIM + (kt) + sg * 8, &sA[b][dA]);        \
    gload16(gh + brow + (size_t)rA * DIM + (kt) + sg * 8, &sBh[b][dA]);       \
    gload16(gl + brow + (size_t)rA * DIM + (kt) + sg * 8, &sBl[b][dA]);       \
    gload16(gh + brow + (size_t)(64 + rA) * DIM + (kt) + sg * 8, &sBh[b][2048 + dA]); \
    gload16(gl + brow + (size_t)(64 + rA) * DIM + (kt) + sg * 8, &sBl[b][2048 + dA]); \
  } while (0)

  STAGE(0, 0);
  __syncthreads();

  for (int t = 0; t < 24; t++) {
    const int cur = t & 1;
    if (t < 23) {
      if (cur) STAGE(0, (t + 1) * 32); else STAGE(1, (t + 1) * 32);
    }
    half8v a8[4], b8h[2], b8l[2];
#pragma unroll
    for (int mf = 0; mf < 4; mf++)
      a8[mf] = *(const half8v*)&sA[cur][(mf * 16 + fr) * 32 + gsw * 8];
#pragma unroll
    for (int nf = 0; nf < 2; nf++) {
      int ro = (w * 32 + nf * 16 + fr) * 32 + gsw * 8;
      b8h[nf] = *(const half8v*)&sBh[cur][ro];
      b8l[nf] = *(const half8v*)&sBl[cur][ro];
    }
#pragma unroll
    for (int mf = 0; mf < 4; mf++)
#pragma unroll
      for (int nf = 0; nf < 2; nf++) {
        f32x4 c = acc[mf][nf];
        c = __builtin_amdgcn_mfma_f32_16x16x32_f16(a8[mf], b8h[nf], c, 0, 0, 0);
        c = __builtin_amdgcn_mfma_f32_16x16x32_f16(a8[mf], b8l[nf], c, 0, 0, 0);
        acc[mf][nf] = c;
      }
    __syncthreads();
  }
#undef STAGE

  const int gm0 = bm * 64;
  const int gn0 = bn * 128 + w * 32;
  const int chunk = bn * 4 + w;   // 0..47
  int gcol[2]; float gbv[2];
#pragma unroll
  for (int nf = 0; nf < 2; nf++) { gcol[nf] = gn0 + nf * 16 + fr; gbv[nf] = gb[gcol[nf]]; }
#pragma unroll
  for (int mf = 0; mf < 4; mf++) {
    float sv[2][4];
#pragma unroll
    for (int nf = 0; nf < 2; nf++)
#pragma unroll
      for (int reg = 0; reg < 4; reg++) {
        int gm = gm0 + mf * 16 + fg * 4 + reg;
        sv[nf][reg] = acc[mf][nf][reg] + gbv[nf] + 0.1f * noise[(size_t)gm * NE + gcol[nf]];
      }
#pragma unroll
    for (int reg = 0; reg < 4; reg++) {
      float m1 = sv[0][reg]; int i1 = gcol[0];
      float m2 = -3e38f; int i2 = 0x7fffffff;
      {
        float v = sv[1][reg]; int ii = gcol[1];
        if (v > m1 || (v == m1 && ii < i1)) { m2 = m1; i2 = i1; m1 = v; i1 = ii; }
        else { m2 = v; i2 = ii; }
      }
#pragma unroll
      for (int off = 1; off <= 8; off <<= 1) {
        float om1 = __shfl_xor(m1, off, 64); int oi1 = __shfl_xor(i1, off, 64);
        float om2 = __shfl_xor(m2, off, 64); int oi2 = __shfl_xor(i2, off, 64);
        top2_merge(m1, i1, m2, i2, om1, oi1, om2, oi2);
      }
      float ssum = __expf(sv[0][reg] - m1) + __expf(sv[1][reg] - m1);
#pragma unroll
      for (int off = 1; off <= 8; off <<= 1) ssum += __shfl_xor(ssum, off, 64);
      if (fr == 0) {
        int gm = gm0 + mf * 16 + fg * 4 + reg;
        part_a[(size_t)gm * 48 + chunk] = make_float4(m1, m2, ssum, __int_as_float(i1));
        part_i2[(size_t)gm * 48 + chunk] = i2;
      }
    }
  }
}

// ---- Kernel 2: merge 48 partials/token -> topw, idx, counts, recheck flags ----
__global__ __launch_bounds__(256) void finalize(
    const float4* __restrict__ part_a, const int* __restrict__ part_i2,
    float* __restrict__ topw, int* __restrict__ idx, int* __restrict__ counts,
    int* __restrict__ rc_count, int* __restrict__ rc_n, int* __restrict__ rc_i2) {
  const int wv = threadIdx.x >> 6, lane = threadIdx.x & 63;
  const int n = blockIdx.x * 4 + wv;
  float m1 = -3e38f, m2 = -3e38f, lm1 = -3e38f, lsum = 0.f;
  int i1 = 0x7fffffff, i2 = 0x7fffffff;
  if (lane < 48) {
    float4 pa = part_a[(size_t)n * 48 + lane];
    m1 = pa.x; m2 = pa.y; lsum = pa.z; i1 = __float_as_int(pa.w);
    i2 = part_i2[(size_t)n * 48 + lane];
    lm1 = pa.x;
  }
#pragma unroll
  for (int off = 1; off <= 32; off <<= 1) {
    float om1 = __shfl_xor(m1, off, 64); int oi1 = __shfl_xor(i1, off, 64);
    float om2 = __shfl_xor(m2, off, 64); int oi2 = __shfl_xor(i2, off, 64);
    top2_merge(m1, i1, m2, i2, om1, oi1, om2, oi2);
  }
  float contrib = (lane < 48) ? __expf(lm1 - m1) * lsum : 0.f;
#pragma unroll
  for (int off = 1; off <= 32; off <<= 1) contrib += __shfl_xor(contrib, off, 64);
  if (lane == 0) {
    topw[n] = 1.0f / contrib;
    idx[n] = i1;
    atomicAdd(counts + i1, 1);
    if (m1 - m2 < GAP_THR) {
      int p = atomicAdd(rc_count, 1);
      rc_n[p] = n; rc_i2[p] = i2;
    }
  }
}

// ---- Kernel 2b: fp32 exact recheck of near-tied top-2 (fixes idx + counts) ----
__global__ __launch_bounds__(256) void recheck(
    const float* __restrict__ x, const float* __restrict__ gw,
    const float* __restrict__ gb, const float* __restrict__ noise,
    const int* __restrict__ rc_n, const int* __restrict__ rc_i2,
    const int* __restrict__ rc_count, int* __restrict__ idx, int* __restrict__ counts) {
  __shared__ float r1[4], r2[4];
  const int cnt = *rc_count;
  const int tid = threadIdx.x;
  const int w = tid >> 6, lane = tid & 63;
  for (int t = blockIdx.x; t < cnt; t += gridDim.x) {
    const int n = rc_n[t];
    const int e1 = idx[n], e2 = rc_i2[t];
    const float* xr = x + (size_t)n * DIM;
    const float* w1 = gw + (size_t)e1 * DIM;
    const float* w2 = gw + (size_t)e2 * DIM;
    float p1 = 0.f, p2 = 0.f;
    for (int k = tid; k < DIM; k += 256) {
      float xv = xr[k];
      p1 += xv * w1[k];
      p2 += xv * w2[k];
    }
#pragma unroll
    for (int off = 32; off; off >>= 1) {
      p1 += __shfl_xor(p1, off, 64);
      p2 += __shfl_xor(p2, off, 64);
    }
    if (lane == 0) { r1[w] = p1; r2[w] = p2; }
    __syncthreads();
    if (tid == 0) {
      float s1 = r1[0] + r1[1] + r1[2] + r1[3] + gb[e1] + 0.1f * noise[(size_t)n * NE + e1];
      float s2 = r2[0] + r2[1] + r2[2] + r2[3] + gb[e2] + 0.1f * noise[(size_t)n * NE + e2];
      if (s2 > s1 || (s2 == s1 && e2 < e1)) {
        idx[n] = e2;
        atomicSub(counts + e1, 1);
        atomicAdd(counts + e2, 1);
      }
    }
    __syncthreads();
  }
}

// ---- Kernel 3: fused scan + 8-token group queue with EMBEDDED token ids ----
// gdesc[g] = 12 ints: [e, cc, pad, pad, tok0..tok7]. One dependent-load level
// in expert_y (no `sorted` indirection). Deterministic output (token results
// independent of slot assignment).
__global__ __launch_bounds__(256) void sortscan(
    const int* __restrict__ counts, const int* __restrict__ idx,
    int* __restrict__ gdesc, int* __restrict__ ngroups) {
  __shared__ int part[256];
  __shared__ int part2[256];
  __shared__ int lcur[NE];
  __shared__ int gtok[NE];
  __shared__ int gbase[NE];
  const int t = threadIdx.x;
  int loc[6];
  int s = 0, s2 = 0;
#pragma unroll
  for (int j = 0; j < 6; j++) {
    loc[j] = counts[t * 6 + j];
    s += loc[j];
    s2 += (loc[j] + 7) >> 3;
  }
  part[t] = s; part2[t] = s2;
  __syncthreads();
  for (int d = 1; d < 256; d <<= 1) {
    int v1 = (t >= d) ? part[t - d] : 0;
    int v2 = (t >= d) ? part2[t - d] : 0;
    __syncthreads();
    part[t] += v1; part2[t] += v2;
    __syncthreads();
  }
  int excl = part[t] - s;
  int excl2 = part2[t] - s2;
#pragma unroll
  for (int j = 0; j < 6; j++) {
    const int e = t * 6 + j, c = loc[j];
    lcur[e] = excl; gtok[e] = excl; gbase[e] = excl2;
    const int ng = (c + 7) >> 3;
    for (int k = 0; k < ng; k++) {
      gdesc[12 * (excl2 + k)]     = e;
      gdesc[12 * (excl2 + k) + 1] = min(8, c - 8 * k);
    }
    excl += c; excl2 += ng;
  }
  if (t == 255) *ngroups = part2[255];
  __syncthreads();
  for (int n = t; n < NT; n += 256) {
    int e = idx[n];
    int pos = atomicAdd(&lcur[e], 1);
    int rel = pos - gtok[e];
    gdesc[12 * (gbase[e] + (rel >> 3)) + 4 + (rel & 7)] = n;
  }
}

// ---- Kernel 4: expert GEMV, one 8-token group per block, W shared x8 ----
// Wave = 16 contiguous W rows (1KB coalesced loads, 2-row prefetch); per row:
// 8 dots (96 FMA) + two 4-token butterflies (14 shfl). W traffic ~= minimum.
__global__ __launch_bounds__(256) void expert_y(
    const float* __restrict__ x, const float* __restrict__ ew,
    const float* __restrict__ eb, const int* __restrict__ gdesc,
    const int* __restrict__ ngroups, float* __restrict__ y) {
  const int g = blockIdx.x;
  if (g >= *ngroups) return;
  const int4 h  = ((const int4*)gdesc)[3 * g];
  const int4 ta = ((const int4*)gdesc)[3 * g + 1];
  const int4 tb = ((const int4*)gdesc)[3 * g + 2];
  const int e = h.x, cc = h.y;
  const int tid = threadIdx.x;
  const int w = tid >> 6, lane = tid & 63;

  int tk[8];
  tk[0] = ta.x;
  tk[1] = (1 < cc) ? ta.y : ta.x;
  tk[2] = (2 < cc) ? ta.z : ta.x;
  tk[3] = (3 < cc) ? ta.w : ta.x;
  tk[4] = (4 < cc) ? tb.x : ta.x;
  tk[5] = (5 < cc) ? tb.y : ta.x;
  tk[6] = (6 < cc) ? tb.z : ta.x;
  tk[7] = (7 < cc) ? tb.w : ta.x;
  const int mytk = (lane == 1) ? tk[1] : (lane == 2) ? tk[2] : (lane == 3) ? tk[3]
                 : (lane == 4) ? tk[4] : (lane == 5) ? tk[5] : (lane == 6) ? tk[6]
                 : (lane == 7) ? tk[7] : tk[0];

  const float4* W4 = (const float4*)(ew + (size_t)e * ED * DIM);
  const float4* X4 = (const float4*)x;
  const float4* Wc = W4 + w * 16 * 192;

  f32x4 xf[8][3];
#pragma unroll
  for (int t = 0; t < 8; t++)
#pragma unroll
    for (int b = 0; b < 3; b++)
      xf[t][b] = *(const f32x4*)&X4[(size_t)tk[t] * 192 + b * 64 + lane];

  f32x4 wb[2][3];
#pragma unroll
  for (int j = 0; j < 3; j++) wb[0][j] = *(const f32x4*)&Wc[j * 64 + lane];
#pragma unroll
  for (int j = 0; j < 3; j++) wb[1][j] = *(const f32x4*)&Wc[192 + j * 64 + lane];

#pragma unroll
  for (int a = 0; a < 16; a++) {
    const int cur = a & 1;
    f32x4 w0 = wb[cur][0], w1 = wb[cur][1], w2 = wb[cur][2];
    if (a < 14) {
      wb[cur][0] = *(const f32x4*)&Wc[(a + 2) * 192 + lane];
      wb[cur][1] = *(const f32x4*)&Wc[(a + 2) * 192 + 64 + lane];
      wb[cur][2] = *(const f32x4*)&Wc[(a + 2) * 192 + 128 + lane];
    }
    float p[8];
#pragma unroll
    for (int t = 0; t < 8; t++) {
      p[t] = w0.x * xf[t][0].x + w0.y * xf[t][0].y + w0.z * xf[t][0].z + w0.w * xf[t][0].w
           + w1.x * xf[t][1].x + w1.y * xf[t][1].y + w1.z * xf[t][1].z + w1.w * xf[t][1].w
           + w2.x * xf[t][2].x + w2.y * xf[t][2].y + w2.z * xf[t][2].z + w2.w * xf[t][2].w;
    }
    const bool b0 = (lane & 1) != 0;
    const bool b1 = (lane & 2) != 0;
    // tokens 0..3
    float qa0 = (b0 ? p[1] : p[0]) + __shfl_xor(b0 ? p[0] : p[1], 1, 64);
    float qa1 = (b0 ? p[3] : p[2]) + __shfl_xor(b0 ? p[2] : p[3], 1, 64);
    float rA = (b1 ? qa1 : qa0) + __shfl_xor(b1 ? qa0 : qa1, 2, 64);
    rA += __shfl_xor(rA, 4, 64);
    rA += __shfl_xor(rA, 8, 64);
    rA += __shfl_xor(rA, 16, 64);
    rA += __shfl_xor(rA, 32, 64);
    // tokens 4..7
    float qb0 = (b0 ? p[5] : p[4]) + __shfl_xor(b0 ? p[4] : p[5], 1, 64);
    float qb1 = (b0 ? p[7] : p[6]) + __shfl_xor(b0 ? p[6] : p[7], 1, 64);
    float rB = (b1 ? qb1 : qb0) + __shfl_xor(b1 ? qb0 : qb1, 2, 64);
    rB += __shfl_xor(rB, 4, 64);
    rB += __shfl_xor(rB, 8, 64);
    rB += __shfl_xor(rB, 16, 64);
    rB += __shfl_xor(rB, 32, 64);

    const int o = w * 16 + a;
    if (lane < cc) {
      y[(size_t)mytk * ED + o] = (lane < 4 ? rA : rB) + eb[e * ED + o];
    }
  }
}

// ---- Kernel 5: projection + scale by top_w ----
__global__ __launch_bounds__(256) void proj_kernel(
    const float* __restrict__ y, const float* __restrict__ pw,
    const float* __restrict__ pb, const float* __restrict__ topw,
    float* __restrict__ out) {
  const int b = blockIdx.x;
  const int tid = threadIdx.x;
  __shared__ float4 ys4[8 * 16];
  __shared__ float tw[8];
  if (tid < 128) {
    int t = tid >> 4, q = tid & 15;
    ys4[tid] = ((const float4*)y)[((size_t)b * 8 + t) * 16 + q];
  }
  if (tid < 8) tw[tid] = topw[b * 8 + tid];
  __syncthreads();
  const float4* pw4 = (const float4*)pw;
#pragma unroll
  for (int c = 0; c < 3; c++) {
    int d = c * 256 + tid;
    float4 pwv[16];
#pragma unroll
    for (int q = 0; q < 16; q++) pwv[q] = pw4[(size_t)d * 16 + q];
    float pbv = pb[d];
    for (int t = 0; t < 8; t++) {
      const float4* yv4 = &ys4[t * 16];
      float s = 0.f;
#pragma unroll
      for (int q = 0; q < 16; q++) {
        float4 yv = yv4[q];
        s += pwv[q].x * yv.x + pwv[q].y * yv.y + pwv[q].z * yv.z + pwv[q].w * yv.w;
      }
      out[((size_t)b * 8 + t) * DIM + d] = (s + pbv) * tw[t];
    }
  }
}

// ---------------- launch ----------------
extern "C" void kernel_launch(void* const* d_in, const int* in_sizes, int n_in,
                              void* d_out, int out_size, void* d_ws, size_t ws_size,
                              hipStream_t stream) {
  const float* x      = (const float*)d_in[0];
  const float* noise  = (const float*)d_in[1];
  const float* gate_w = (const float*)d_in[2];
  const float* gate_b = (const float*)d_in[3];
  const float* ew     = (const float*)d_in[4];
  const float* eb     = (const float*)d_in[5];
  const float* pw     = (const float*)d_in[6];
  const float* pb     = (const float*)d_in[7];
  float* out = (float*)d_out;

  char* ws = (char*)d_ws;
  _Float16* xh     = (_Float16*)(ws);                 // 6291456
  _Float16* gh     = (_Float16*)(ws + 6291456);       // 2359296
  _Float16* gl     = (_Float16*)(ws + 8650752);       // 2359296
  float4*   part_a = (float4*)(ws + 11010048);        // 3145728
  int*      part_i2= (int*)   (ws + 14155776);        //  786432
  float*    y      = (float*)  (ws + 14942208);       // 1048576
  float*    topw   = (float*)  (ws + 15990784);       //   16384
  int*      idx    = (int*)    (ws + 16007168);       //   16384
  int*      counts = (int*)    (ws + 16023552);       //    6144
  int*      rc_cnt = (int*)    (ws + 16029696);       //     256
  int*      rc_n   = (int*)    (ws + 16029952);       //   16384
  int*      rc_i2  = (int*)    (ws + 16046336);       //   16384
  int*      ngroups= (int*)    (ws + 16062720);       //     256
  int*      gdesc  = (int*)    (ws + 16062976);       //   92160 (1920 x 12 ints)

  split_all<<<(NT * DIM / 4 + NE * DIM / 4 + 255) / 256, 256, 0, stream>>>(
      x, gate_w, xh, gh, gl, rc_cnt, counts);
  gate_mfma<<<dim3(NT / 64, NE / 128), 256, 0, stream>>>(
      xh, gh, gl, gate_b, noise, part_a, part_i2);
  finalize<<<NT / 4, 256, 0, stream>>>(part_a, part_i2, topw, idx, counts,
                                       rc_cnt, rc_n, rc_i2);
  recheck<<<64, 256, 0, stream>>>(x, gate_w, gate_b, noise, rc_n, rc_i2, rc_cnt,
                                  idx, counts);
  sortscan<<<1, 256, 0, stream>>>(counts, idx, gdesc, ngroups);
  expert_y<<<MAXG, 256, 0, stream>>>(x, ew, eb, gdesc, ngroups, y);
  proj_kernel<<<NT / 8, 256, 0, stream>>>(y, pw, pb, topw, out);
}